// Round 9
// baseline (398.424 us; speedup 1.0000x reference)
//
#include <hip/hip_runtime.h>
#include <math.h>

// Problem dims (fixed by the reference)
#define BN    32          // batch
#define TN    512         // TFs
#define GN    2000        // genes
#define PPGN  10          // peaks per gene
#define PN    (GN*PPGN)   // 20000 peaks
#define EN    64000       // edges
#define NOUTN 10          // output channels
#define PQN   (PN/4)      // 5000 p-quads (float4 granules)

#define TCH   8           // number of t-chunks
#define TPC   (TN/TCH)    // 64 t per chunk
#define NK    10          // p-quads per thread (512 thr: 512*10 >= 5000)

typedef float float4v __attribute__((ext_vector_type(4)));

// Stage 1 (R8 post-mortem): 4 configs (R4/R6/R8) converge at ~4.5 TB/s HBM
// regardless of occupancy/ILP/blocking -> suspect DRAM/fabric efficiency of
// the MULTI-STREAM STRIDED pattern (80KB hops per t-step, 41MB between
// b-streams) vs the linear sweeps that hit 6.3-6.4 (copy/fill µbenches).
// This round: one block = one CONTIGUOUS 5.12MB slab of x (fixed b, 64 t,
// all p), read front-to-back in address order. 512 thr x 10 quads each cover
// a t-row (80KB); t-rows adjacent. Grid (b fast 32, tc 8) = 256 blocks ->
// the 32 blocks sharing a tc are dispatch-adjacent (4/XCD) and read the SAME
// 5.12MB W slab -> L2/L3-served, HBM ~once. x nt (stream), W cached.
// Structural traffic ~1.45GB; at 6.3TB/s -> ~230us kpp.
__global__ __launch_bounds__(512)
void k_perpeak(const float* __restrict__ x,
               const float* __restrict__ W_sub,
               float* __restrict__ partial) {
    int b  = blockIdx.x;                // 0..31 (fast axis)
    int tc = blockIdx.y;                // 0..7
    int t0 = tc * TPC;

    const float4v* xp = (const float4v*)x + ((size_t)b * TN + t0) * PQN;
    const float4v* wp = (const float4v*)W_sub + (size_t)t0 * PQN;

    float4v acc[NK];
#pragma unroll
    for (int k = 0; k < NK; ++k) acc[k] = (float4v){0.f, 0.f, 0.f, 0.f};

#pragma unroll 1
    for (int t = 0; t < TPC; ++t) {
        const float4v* xr = xp + (size_t)t * PQN;
        const float4v* wr = wp + (size_t)t * PQN;
#pragma unroll
        for (int k = 0; k < NK; ++k) {
            int p = (int)threadIdx.x + 512 * k;
            if (p < PQN) {
                float4v xv = __builtin_nontemporal_load(xr + p);
                float4v wv = wr[p];
                acc[k] = xv * wv + acc[k];
            }
        }
    }

    float4v* pp = (float4v*)partial + ((size_t)tc * BN + b) * PQN;
#pragma unroll
    for (int k = 0; k < NK; ++k) {
        int p = (int)threadIdx.x + 512 * k;
        if (p < PQN)
            __builtin_nontemporal_store(acc[k], pp + p);
    }
}

// Stage 2: h[b,g] = relu(b_sub[g] + sum_tc sum_{k<10} partial[tc][b][g*10+k])
__global__ void k_h(const float* __restrict__ partial,
                    const float* __restrict__ b_sub,
                    float* __restrict__ h) {
    int idx = blockIdx.x * blockDim.x + threadIdx.x;
    if (idx >= BN * GN) return;
    int g = idx % GN, b = idx / GN;
    float s = b_sub[g];
    for (int tc = 0; tc < TCH; ++tc) {
        const float* pp = partial + ((size_t)tc * BN + b) * PN + g * PPGN;
#pragma unroll
        for (int k = 0; k < PPGN; ++k) s += pp[k];
    }
    h[idx] = fmaxf(s, 0.0f);
}

// Stage 3a: degree of target nodes (col)
__global__ void k_deg(const int* __restrict__ col, float* __restrict__ deg) {
    int e = blockIdx.x * blockDim.x + threadIdx.x;
    if (e < EN) atomicAdd(&deg[col[e]], 1.0f);
}

// Stage 3b: dinv = deg^-1/2 (0 where deg == 0)
__global__ void k_dinv(const float* __restrict__ deg, float* __restrict__ dinv) {
    int g = blockIdx.x * blockDim.x + threadIdx.x;
    if (g < GN) {
        float d = deg[g];
        dinv[g] = (d > 0.0f) ? (1.0f / sqrtf(d)) : 0.0f;
    }
}

// Stage 3c: s[b,g] = sum_{e: col[e]==g} dinv[row]*dinv[col] * h[b,row]
// One block per batch; accumulate in LDS (8KB) with LDS atomics, single
// non-atomic writeback.
__global__ __launch_bounds__(256)
void k_s(const int* __restrict__ row, const int* __restrict__ col,
         const float* __restrict__ dinv, const float* __restrict__ h,
         float* __restrict__ s) {
    __shared__ float s_lds[GN];
    int b = blockIdx.x;
    for (int g = threadIdx.x; g < GN; g += 256) s_lds[g] = 0.0f;
    __syncthreads();
    const float* hb = h + (size_t)b * GN;
    for (int e = threadIdx.x; e < EN; e += 256) {
        int r = row[e], c = col[e];
        float nrm = dinv[r] * dinv[c];
        atomicAdd(&s_lds[c], nrm * hb[r]);
    }
    __syncthreads();
    for (int g = threadIdx.x; g < GN; g += 256)
        s[(size_t)b * GN + g] = s_lds[g];
}

// Stage 4: out[b,n] = sum_g sum_c relu(W_gcn[c]*s[b,g]+b_gcn[c]) * W_out[n,2g+c] + b_out[n]
// One wave (64 threads) per (b,n).
__global__ void k_out(const float* __restrict__ s,
                      const float* __restrict__ W_gcn,
                      const float* __restrict__ b_gcn,
                      const float* __restrict__ W_out,
                      const float* __restrict__ b_out,
                      float* __restrict__ out) {
    int b = blockIdx.x / NOUTN;
    int n = blockIdx.x % NOUTN;
    int lane = threadIdx.x;

    float w0 = W_gcn[0], w1 = W_gcn[1];
    float c0 = b_gcn[0], c1 = b_gcn[1];

    float acc = 0.0f;
    for (int g = lane; g < GN; g += 64) {
        float sv = s[(size_t)b * GN + g];
        float g0 = fmaxf(fmaf(sv, w0, c0), 0.0f);
        float g1 = fmaxf(fmaf(sv, w1, c1), 0.0f);
        const float* wo = &W_out[(size_t)n * (GN * 2) + 2 * g];
        acc = fmaf(g0, wo[0], acc);
        acc = fmaf(g1, wo[1], acc);
    }
#pragma unroll
    for (int off = 32; off > 0; off >>= 1)
        acc += __shfl_down(acc, off);
    if (lane == 0) out[b * NOUTN + n] = acc + b_out[n];
}

extern "C" void kernel_launch(void* const* d_in, const int* in_sizes, int n_in,
                              void* d_out, int out_size, void* d_ws, size_t ws_size,
                              hipStream_t stream) {
    const float* x         = (const float*)d_in[0];
    const int*   edge_index= (const int*)  d_in[1];
    const float* W_sub     = (const float*)d_in[2];
    const float* b_sub     = (const float*)d_in[3];
    const float* W_gcn     = (const float*)d_in[4];
    const float* b_gcn     = (const float*)d_in[5];
    const float* W_out     = (const float*)d_in[6];
    const float* b_out     = (const float*)d_in[7];
    float* out = (float*)d_out;

    char* ws = (char*)d_ws;
    // partial: TCH*BN*PN floats = 8*32*20000*4B = 20,480,000 B
    float* partial = (float*)(ws);
    float* h       = (float*)(ws + 20480000);       // B*G floats = 256,000 B
    float* deg     = (float*)(ws + 20736000);       // G   floats =   8,000 B
    float* dinv    = (float*)(ws + 20744000);       // G   floats =   8,000 B
    float* s       = (float*)(ws + 20752000);       // B*G floats = 256,000 B

    const int* row = edge_index;        // edge_index[0,:]
    const int* col = edge_index + EN;   // edge_index[1,:]

    // deg is atomically accumulated -> zero it every call (graph-capture legal)
    hipMemsetAsync(deg, 0, GN * sizeof(float), stream);

    dim3 grid_pp(BN, TCH);   // x = b (fast, 32), y = t-chunk (8)
    k_perpeak<<<grid_pp, 512, 0, stream>>>(x, W_sub, partial);
    k_h      <<<((BN * GN) + 255) / 256, 256, 0, stream>>>(partial, b_sub, h);
    k_deg    <<<(EN + 255) / 256,        256, 0, stream>>>(col, deg);
    k_dinv   <<<(GN + 255) / 256,        256, 0, stream>>>(deg, dinv);
    k_s      <<<BN, 256, 0, stream>>>(row, col, dinv, h, s);
    k_out    <<<BN * NOUTN, 64, 0, stream>>>(s, W_gcn, b_gcn, W_out, b_out, out);
}